// Round 19
// baseline (147.449 us; speedup 1.0000x reference)
//
#include <hip/hip_runtime.h>
#include <hip/hip_bf16.h>
#include <math.h>

#define PROJ_EPSF 0.004f
#define MIN_NORMF 1e-15f
#define ATANH_EPSF 1e-5f
#define WEI_EPSF 1e-3f
#define LN2F 0.69314718055994531f

#define TT 1024
#define CC 768
#define HH 12
#define BBATCH 4

typedef unsigned long long ull;
typedef __attribute__((ext_vector_type(4))) float f32x4;
typedef __attribute__((ext_vector_type(8))) short bf16x8;

#define MFMA(a, b, c) __builtin_amdgcn_mfma_f32_16x16x32_bf16(a, b, c, 0, 0, 0)

static __device__ __forceinline__ uint cvtpk(float a, float b) {
    uint r;
    asm("v_cvt_pk_bf16_f32 %0, %1, %2" : "=v"(r) : "v"(a), "v"(b));
    return r;
}
static __device__ __forceinline__ ushort f2bf(float f) {
    uint u = __float_as_uint(f);
    u += 0x7fffu + ((u >> 16) & 1u);
    return (ushort)(u >> 16);
}
static __device__ __forceinline__ float bf2f(ushort h) {
    return __uint_as_float(((uint)h) << 16);
}
static __device__ __forceinline__ void split4(const float4& f, ull& hp, ull& lp) {
    uint h01 = cvtpk(f.x, f.y), h23 = cvtpk(f.z, f.w);
    float r0 = f.x - __uint_as_float(h01 << 16);
    float r1 = f.y - __uint_as_float(h01 & 0xffff0000u);
    float r2 = f.z - __uint_as_float(h23 << 16);
    float r3 = f.w - __uint_as_float(h23 & 0xffff0000u);
    uint l01 = cvtpk(r0, r1), l23 = cvtpk(r2, r3);
    hp = ((ull)h23 << 32) | h01;
    lp = ((ull)l23 << 32) | l01;
}
union pk16 { bf16x8 v; ull u[2]; };
static __device__ __forceinline__ void gl_lds16(const void* g, void* l) {
    __builtin_amdgcn_global_load_lds(
        (const __attribute__((address_space(1))) unsigned int*)g,
        (__attribute__((address_space(3))) unsigned int*)l, 16, 0, 0);
}

// ---------------- prep: weights (+x when PS) -> bf16 hi/lo planes ----------------
__global__ __launch_bounds__(256) void wprep2(const float* __restrict__ Wq,
                                              const float* __restrict__ Wp,
                                              const float* __restrict__ x,
                                              ushort* __restrict__ Wqh,
                                              ushort* __restrict__ Wql,
                                              ushort* __restrict__ Wph,
                                              ushort* __restrict__ Wpl,
                                              ushort* __restrict__ xh,
                                              ushort* __restrict__ xl) {
    const int n1 = 2304 * CC / 4;
    const int n2 = CC * CC / 4;
    const int n3 = 4096 * CC / 4;
    int i = blockIdx.x * 256 + threadIdx.x;
    if (i < n1) {
        float4 f = ((const float4*)Wq)[i];
        ull hp, lp;
        split4(f, hp, lp);
        ((ull*)Wqh)[i] = hp;
        ((ull*)Wql)[i] = lp;
    } else if (i < n1 + n2) {
        int j = i - n1;
        float4 f = ((const float4*)Wp)[j];
        ull hp, lp;
        split4(f, hp, lp);
        ((ull*)Wph)[j] = hp;
        ((ull*)Wpl)[j] = lp;
    } else if (xh && i < n1 + n2 + n3) {
        int j = i - n1 - n2;
        float4 f = ((const float4*)x)[j];
        ull hp, lp;
        split4(f, hp, lp);
        ((ull*)xh)[j] = hp;
        ((ull*)xl)[j] = lp;
    }
}

// ---------------- fused QKV GEMM ----------------
// PS=true: pure gl_lds, TRIPLE-buffered 2-deep pipeline, counted vmcnt,
// 1 barrier/iter.  PS=false: R15 fallback (A reg-split, dbuf).
template <bool PS>
__global__ __launch_bounds__(256) void gemm_qkv(
        const float* __restrict__ x, const ushort* __restrict__ xhp,
        const ushort* __restrict__ xlp, const ushort* __restrict__ Wh,
        const ushort* __restrict__ Wl, const float* __restrict__ kcurv,
        ushort* __restrict__ qh, ushort* __restrict__ ql,
        ushort* __restrict__ kh, ushort* __restrict__ kl,
        ushort* __restrict__ vT, float* __restrict__ x2g,
        float* __restrict__ y2g) {
    __shared__ ushort SS[3][4][4096];   // 96 KB; epilogue reuses first 64 KB
    const int tid = threadIdx.x, lane = tid & 63, wv = tid >> 6;
    const int wr = wv >> 1, wc = wv & 1, lr = lane & 15, lg = lane >> 4;
    const int m0 = blockIdx.x * 128, n0 = blockIdx.y * 128;
    const bool isV = (n0 >= 2 * CC);

    const int c0 = 2 * wv, c1 = 2 * wv + 1;
    const int p0 = 8 * c0 + (lane >> 3), q0 = (lane & 7) ^ (p0 & 7);
    const int p1 = 8 * c1 + (lane >> 3), q1 = (lane & 7) ^ (p1 & 7);
    const size_t bs0 = (size_t)(n0 + 2 * p0 + (q0 >> 2)) * CC + (q0 & 3) * 8;
    const size_t bs1 = (size_t)(n0 + 2 * p1 + (q1 >> 2)) * CC + (q1 & 3) * 8;
    const size_t as0 = (size_t)(m0 + 2 * p0 + (q0 >> 2)) * CC + (q0 & 3) * 8;
    const size_t as1 = (size_t)(m0 + 2 * p1 + (q1 >> 2)) * CC + (q1 & 3) * 8;
    const int arow = tid >> 1, akh = tid & 1;
    const float* Ap = x + (size_t)(m0 + arow) * CC + akh * 16;
    const int ap_ = arow >> 1;
    const int ag0 = 4 * (arow & 1) + 2 * akh;
    const int aoff0 = ap_ * 128 + ((ag0 ^ (ap_ & 7)) << 4);
    const int aoff1 = ap_ * 128 + (((ag0 + 1) ^ (ap_ & 7)) << 4);
    const int goff = (((4 * (lr & 1) + lg) ^ ((lr >> 1) & 7)) << 4);
    const int pa = wr * 32 + (lr >> 1);
    const int pb = wc * 32 + (lr >> 1);

    f32x4 acc[4][4] = {};
    float4 av[4];

#define STAGE_B(BUF, KK)                                                          \
    gl_lds16(Wh + bs0 + (KK), (char*)SS[BUF][2] + c0 * 1024);                     \
    gl_lds16(Wh + bs1 + (KK), (char*)SS[BUF][2] + c1 * 1024);                     \
    if (!isV) {                                                                   \
        gl_lds16(Wl + bs0 + (KK), (char*)SS[BUF][3] + c0 * 1024);                 \
        gl_lds16(Wl + bs1 + (KK), (char*)SS[BUF][3] + c1 * 1024);                 \
    }
#define STAGE_APS(BUF, KK)                                                        \
    gl_lds16(xhp + as0 + (KK), (char*)SS[BUF][0] + c0 * 1024);                    \
    gl_lds16(xhp + as1 + (KK), (char*)SS[BUF][0] + c1 * 1024);                    \
    if (!isV) {                                                                   \
        gl_lds16(xlp + as0 + (KK), (char*)SS[BUF][1] + c0 * 1024);                \
        gl_lds16(xlp + as1 + (KK), (char*)SS[BUF][1] + c1 * 1024);                \
    }
#define SPLIT_A(BUF)                                                              \
    {                                                                             \
        pk16 h_, l_;                                                              \
        split4(av[0], h_.u[0], l_.u[0]);                                          \
        split4(av[1], h_.u[1], l_.u[1]);                                          \
        *(bf16x8*)((char*)SS[BUF][0] + aoff0) = h_.v;                             \
        if (!isV) *(bf16x8*)((char*)SS[BUF][1] + aoff0) = l_.v;                   \
        split4(av[2], h_.u[0], l_.u[0]);                                          \
        split4(av[3], h_.u[1], l_.u[1]);                                          \
        *(bf16x8*)((char*)SS[BUF][0] + aoff1) = h_.v;                             \
        if (!isV) *(bf16x8*)((char*)SS[BUF][1] + aoff1) = l_.v;                   \
    }
#define LOAD_A(KK)                                                                \
    { _Pragma("unroll") for (int q = 0; q < 4; ++q)                               \
        av[q] = *(const float4*)(Ap + (KK) + 4 * q); }
#define DO_MFMA(BUF)                                                              \
    if (!isV) {                                                                   \
        bf16x8 a_h[4], a_l[4];                                                    \
        _Pragma("unroll") for (int m = 0; m < 4; ++m) {                           \
            const int off = (pa + m * 8) * 128 + goff;                            \
            a_h[m] = *(const bf16x8*)((char*)SS[BUF][0] + off);                   \
            a_l[m] = *(const bf16x8*)((char*)SS[BUF][1] + off);                   \
        }                                                                         \
        _Pragma("unroll") for (int n = 0; n < 4; ++n) {                           \
            const int off = (pb + n * 8) * 128 + goff;                            \
            bf16x8 b_h = *(const bf16x8*)((char*)SS[BUF][2] + off);               \
            bf16x8 b_l = *(const bf16x8*)((char*)SS[BUF][3] + off);               \
            _Pragma("unroll") for (int m = 0; m < 4; ++m) {                       \
                acc[m][n] = MFMA(a_h[m], b_h, acc[m][n]);                         \
                acc[m][n] = MFMA(a_h[m], b_l, acc[m][n]);                         \
                acc[m][n] = MFMA(a_l[m], b_h, acc[m][n]);                         \
            }                                                                     \
        }                                                                         \
    } else {                                                                      \
        bf16x8 a_h[4], b_h[4];                                                    \
        _Pragma("unroll") for (int m = 0; m < 4; ++m)                             \
            a_h[m] = *(const bf16x8*)((char*)SS[BUF][0] + (pa + m * 8) * 128 + goff); \
        _Pragma("unroll") for (int n = 0; n < 4; ++n)                             \
            b_h[n] = *(const bf16x8*)((char*)SS[BUF][2] + (pb + n * 8) * 128 + goff); \
        _Pragma("unroll") for (int n = 0; n < 4; ++n)                             \
            _Pragma("unroll") for (int m = 0; m < 4; ++m)                         \
                acc[n][m] = MFMA(b_h[n], a_h[m], acc[n][m]);                      \
    }

    if constexpr (PS) {
        // ---- triple-buffer 2-deep pipeline, counted vmcnt, 1 barrier/iter ----
        STAGE_APS(0, 0)  STAGE_B(0, 0)
        STAGE_APS(1, 32) STAGE_B(1, 32)
        if (!isV) asm volatile("s_waitcnt vmcnt(8)" ::: "memory");
        else      asm volatile("s_waitcnt vmcnt(4)" ::: "memory");
        __builtin_amdgcn_s_barrier();
        __builtin_amdgcn_sched_barrier(0);
        int it = 0;
        for (int kk = 0; kk < CC; kk += 32, ++it) {
            const int cb = it % 3;
            if (kk + 64 < CC) {
                const int nb = (it + 2) % 3;   // freed by previous barrier
                STAGE_APS(nb, kk + 64) STAGE_B(nb, kk + 64)
                __builtin_amdgcn_sched_barrier(0);
            }
            DO_MFMA(cb)
            if (kk + 64 < CC) {
                if (!isV) asm volatile("s_waitcnt vmcnt(8)" ::: "memory");
                else      asm volatile("s_waitcnt vmcnt(4)" ::: "memory");
            } else if (kk + 32 < CC) {
                asm volatile("s_waitcnt vmcnt(0)" ::: "memory");
            }
            if (kk + 32 < CC) {
                __builtin_amdgcn_s_barrier();
                __builtin_amdgcn_sched_barrier(0);
            }
        }
    } else {
        // ---- fallback (R15): A reg-split, dbuf over bufs 0/1 ----
        int cur = 0;
        LOAD_A(0)
        STAGE_B(0, 0)
        SPLIT_A(0)
        LOAD_A(32)
        asm volatile("s_waitcnt vmcnt(4) lgkmcnt(0)" ::: "memory");
        __builtin_amdgcn_s_barrier();
        __builtin_amdgcn_sched_barrier(0);
        for (int kk = 0; kk < CC; kk += 32) {
            const bool notLast = (kk + 32 < CC);
            if (notLast) {
                STAGE_B(cur ^ 1, kk + 32)
                SPLIT_A(cur ^ 1)
                if (kk + 64 < CC) LOAD_A(kk + 64)
                __builtin_amdgcn_sched_barrier(0);
            }
            DO_MFMA(cur)
            if (notLast) {
                if (kk + 64 < CC)
                    asm volatile("s_waitcnt vmcnt(4) lgkmcnt(0)" ::: "memory");
                else
                    asm volatile("s_waitcnt vmcnt(0) lgkmcnt(0)" ::: "memory");
                __builtin_amdgcn_s_barrier();
                __builtin_amdgcn_sched_barrier(0);
            }
            cur ^= 1;
        }
    }
#undef STAGE_B
#undef STAGE_APS
#undef SPLIT_A
#undef LOAD_A
#undef DO_MFMA

    // ---- epilogue: per-wave LDS re-layout -> coalesced b128 stores ----
    __syncthreads();
    ushort* Shi = (ushort*)SS + (size_t)wv * 8192;
    ushort* Slo = Shi + 4096;
    const int rl = lane >> 3, cg = lane & 7;
    if (isV) {
        const int hd = (n0 - 2 * CC) / 64 + wc;
#pragma unroll
        for (int n = 0; n < 4; ++n)
#pragma unroll
            for (int m = 0; m < 4; ++m)
#pragma unroll
                for (int r = 0; r < 4; ++r)
                    Shi[(n * 16 + lg * 4 + r) * 64 + m * 16 + lr] = f2bf(acc[n][m][r]);
#pragma unroll
        for (int q = 0; q < 8; ++q) {
            const int dlr = q * 8 + rl;
            *(bf16x8*)&vT[(size_t)(hd * 64 + dlr) * 4096 + m0 + wr * 64 + cg * 8] =
                *(const bf16x8*)&Shi[dlr * 64 + cg * 8];
        }
    } else {
        const bool isQ = (n0 < CC);
        const int hd = (isQ ? n0 : n0 - CC) / 64 + wc;
        ushort* ph = isQ ? qh : kh;
        ushort* pl = isQ ? ql : kl;
        float* sg = isQ ? x2g : y2g;
        const float kcv = kcurv[hd];
        const float mxn = (1.0f - PROJ_EPSF) / sqrtf(kcv);
        const float mxn2 = mxn * mxn;
#pragma unroll
        for (int m = 0; m < 4; ++m)
#pragma unroll
            for (int r = 0; r < 4; ++r) {
                float s = 0.f;
#pragma unroll
                for (int n = 0; n < 4; ++n) s = fmaf(acc[m][n][r], acc[m][n][r], s);
                s += __shfl_xor(s, 1);
                s += __shfl_xor(s, 2);
                s += __shfl_xor(s, 4);
                s += __shfl_xor(s, 8);
                float scale = 1.0f, x2v = s;
                if (s > mxn2) {
                    scale = mxn * __builtin_amdgcn_rcpf(sqrtf(s));
                    x2v = s * scale * scale;
                }
                const int row = m * 16 + lg * 4 + r;
#pragma unroll
                for (int n = 0; n < 4; ++n) {
                    const float v = acc[m][n][r] * scale;
                    const ushort hb = f2bf(v);
                    Shi[row * 64 + n * 16 + lr] = hb;
                    Slo[row * 64 + n * 16 + lr] = f2bf(v - bf2f(hb));
                }
                if (lr == 0) {
                    const int tok = m0 + wr * 64 + row;
                    sg[(size_t)((tok >> 10) * HH + hd) * TT + (tok & 1023)] = x2v;
                }
            }
        const size_t cb2 = (size_t)(isQ ? n0 : n0 - CC) + wc * 64;
#pragma unroll
        for (int q = 0; q < 8; ++q) {
            const int row = q * 8 + rl;
            const size_t gb = (size_t)(m0 + wr * 64 + row) * CC + cb2 + cg * 8;
            *(bf16x8*)&ph[gb] = *(const bf16x8*)&Shi[row * 64 + cg * 8];
            *(bf16x8*)&pl[gb] = *(const bf16x8*)&Slo[row * 64 + cg * 8];
        }
    }
}

// ---------------- 4-wave LDS-staged attention (R16/R18 structure) ----------------
__global__ __launch_bounds__(256) void hyp_attn(
        const ushort* __restrict__ qh, const ushort* __restrict__ ql,
        const ushort* __restrict__ kh, const ushort* __restrict__ kl,
        const ushort* __restrict__ vT, const float* __restrict__ x2g,
        const float* __restrict__ y2g, const float* __restrict__ kcurv,
        ushort* __restrict__ yh, ushort* __restrict__ yl) {
    const int ib = (int)blockIdx.x;          // 0..767
    const int xcd = ib & 7, t = ib >> 3;
    const int tcr = t / 6;
    const int which = t - tcr * 6;
    const int g64 = 15 - tcr;
    const int bh = which * 8 + xcd;
    const int b = bh / HH, h = bh - b * HH;
    const int tid = threadIdx.x, lane = tid & 63, wv = tid >> 6;
    const int lr = lane & 15, lg = lane >> 4;
    const int rg = g64 * 4 + wv;
    const int rgq = g64;

    __shared__ char ldsK[2][16384];
    __shared__ char ldsV[8192];
    __shared__ ushort wtb[4][16 * 72];
    ushort* wtw = wtb[wv];

    const float kc = kcurv[h];
    const float sk = sqrtf(kc);
    const float distc = LN2F / sk;
    const float d2c = distc * distc;
    const float twokc = 2.0f * kc;
    const float cA = 1.0f - ATANH_EPSF;

    const size_t qrb = (size_t)(b * TT + rg * 16 + lr) * CC + h * 64 + lg * 8;
    const bf16x8 qH0 = *(const bf16x8*)(qh + qrb), qH1 = *(const bf16x8*)(qh + qrb + 32);
    const bf16x8 qL0 = *(const bf16x8*)(ql + qrb), qL1 = *(const bf16x8*)(ql + qrb + 32);
    const float4 x2v = *(const float4*)&x2g[(size_t)bh * TT + rg * 16 + lg * 4];
    const float x2a[4] = { x2v.x, x2v.y, x2v.z, x2v.w };
    float kx2[4], Bc[4], Bc2[4];
#pragma unroll
    for (int r = 0; r < 4; ++r) {
        kx2[r] = kc * x2a[r];
        Bc[r] = 1.0f - kx2[r];
        Bc2[r] = Bc[r] * Bc[r];
    }

    const int srow8 = lane >> 3;
    const int sgrp = (lane & 7) ^ (srow8 & 7);
    const int so0 = ((lg ^ (lr & 7)) << 4);
    const int so1 = (((4 + lg) ^ (lr & 7)) << 4);
    const int lro = lr << 7;

#define STAGE_K(BUF, J0)                                                          \
    { _Pragma("unroll") for (int c4 = 0; c4 < 2; ++c4) {                          \
        const int c = wv * 2 + c4;                                                \
        const size_t gsrc = (size_t)(b * TT + (J0) + c * 8 + srow8) * CC + h * 64 + sgrp * 8; \
        gl_lds16(kh + gsrc, (char*)(BUF) + c * 1024);                             \
        gl_lds16(kl + gsrc, (char*)(BUF) + 8192 + c * 1024);                      \
    } }
#define STAGE_V(J0)                                                               \
    { _Pragma("unroll") for (int c4 = 0; c4 < 2; ++c4) {                          \
        const int c = wv * 2 + c4;                                                \
        gl_lds16(vT + (size_t)(h * 64 + c * 8 + srow8) * 4096 + b * TT + (J0) + sgrp * 8, \
                 ldsV + c * 1024);                                                \
    } }

#define TRBODY(NN, SA, Y2R, MASKED)                                                \
    {                                                                              \
        const float ky2 = kc * (Y2R);                                              \
        const float p1 = 1.0f + ky2;                                               \
        _Pragma("unroll") for (int r = 0; r < 4; ++r) {                            \
            const float xy = SA[r];                                                \
            const float t2 = twokc * xy;                                           \
            const float Aa = p1 - t2;                                              \
            const float dn = fmaxf(fmaf(kx2[r], ky2, 1.0f) - t2, MIN_NORMF);       \
            const float AaBc = Aa * Bc[r];                                         \
            const float c1 = fmaf(-AaBc, t2, Bc2[r] * ky2);                        \
            const float num2k = fmaf(Aa * Aa, kx2[r], c1);                         \
            const float s = sqrtf(fmaxf(num2k, MIN_NORMF));                        \
            const float sm = fminf(s, cA * dn);                                    \
            const float L = __builtin_amdgcn_logf(dn + sm) -                       \
                            __builtin_amdgcn_logf(dn - sm);                        \
            float w = __builtin_amdgcn_rcpf(fmaf(L * L, d2c, WEI_EPSF));           \
            if (MASKED && (j0 + NN * 16 + lr > rg * 16 + lg * 4 + r)) w = 0.0f;    \
            wtw[(lg * 4 + r) * 72 + NN * 16 + lr] = f2bf(w);                       \
            wsum[r] += w;                                                          \
        }                                                                          \
    }

#define SMFMA(CUR)                                                                 \
    f32x4 sacc[4] = {};                                                            \
    { _Pragma("unroll") for (int n = 0; n < 4; ++n) {                              \
        const char* p = ldsK[CUR] + n * 2048 + lro;                                \
        bf16x8 h0 = *(const bf16x8*)(p + so0);                                     \
        bf16x8 h1 = *(const bf16x8*)(p + so1);                                     \
        bf16x8 l0 = *(const bf16x8*)(p + 8192 + so0);                              \
        bf16x8 l1 = *(const bf16x8*)(p + 8192 + so1);                              \
        sacc[n] = MFMA(qH0, h0, sacc[n]);                                          \
        sacc[n] = MFMA(qH0, l0, sacc[n]);                                          \
        sacc[n] = MFMA(qL0, h0, sacc[n]);                                          \
        sacc[n] = MFMA(qH1, h1, sacc[n]);                                          \
        sacc[n] = MFMA(qH1, l1, sacc[n]);                                          \
        sacc[n] = MFMA(qL1, h1, sacc[n]);                                          \
    } }

#define PVMFMA                                                                     \
    { bf16x8 pw0 = *(const bf16x8*)&wtw[lr * 72 + lg * 8];                         \
      bf16x8 pw1 = *(const bf16x8*)&wtw[lr * 72 + 32 + lg * 8];                    \
      _Pragma("unroll") for (int n = 0; n < 4; ++n) {                              \
          const char* p = ldsV + n * 2048 + lro;                                   \
          bf16x8 v0 = *(const bf16x8*)(p + so0);                                   \
          bf16x8 v1 = *(const bf16x8*)(p + so1);                                   \
          pv[n] = MFMA(pw0, v0, pv[n]);                                            \
          pv[n] = MFMA(pw1, v1, pv[n]);                                            \
      } }

    f32x4 pv[4] = {};
    float wsum[4] = {};

    STAGE_K(ldsK[0], 0)

    int cur = 0;
    for (int jt = 0; jt < rgq; ++jt) {       // mask-free main tiles
        const int j0 = jt * 64;
        STAGE_V(j0)
        STAGE_K(ldsK[cur ^ 1], j0 + 64)
        asm volatile("s_waitcnt vmcnt(6)" ::: "memory");
        __builtin_amdgcn_s_barrier();
        __builtin_amdgcn_sched_barrier(0);
        const size_t y2b = (size_t)bh * TT + j0 + lr;
        const float y2n[4] = { y2g[y2b], y2g[y2b + 16], y2g[y2b + 32], y2g[y2b + 48] };
        __builtin_amdgcn_s_setprio(1);
        SMFMA(cur)
        TRBODY(0, sacc[0], y2n[0], false)
        TRBODY(1, sacc[1], y2n[1], false)
        TRBODY(2, sacc[2], y2n[2], false)
        TRBODY(3, sacc[3], y2n[3], false)
        __builtin_amdgcn_s_setprio(0);
        asm volatile("s_waitcnt vmcnt(4)" ::: "memory");
        __builtin_amdgcn_s_barrier();
        __builtin_amdgcn_sched_barrier(0);
        __builtin_amdgcn_s_setprio(1);
        PVMFMA
        __builtin_amdgcn_s_setprio(0);
        __builtin_amdgcn_s_barrier();
        cur ^= 1;
    }
    {   // peeled diagonal tile (causal mask active)
        const int j0 = rgq * 64;
        STAGE_V(j0)
        asm volatile("s_waitcnt vmcnt(2)" ::: "memory");
        __builtin_amdgcn_s_barrier();
        __builtin_amdgcn_sched_barrier(0);
        const size_t y2b = (size_t)bh * TT + j0 + lr;
        const float y2n[4] = { y2g[y2b], y2g[y2b + 16], y2g[y2b + 32], y2g[y2b + 48] };
        __builtin_amdgcn_s_setprio(1);
        SMFMA(cur)
        TRBODY(0, sacc[0], y2n[0], true)
        TRBODY(1, sacc[1], y2n[1], true)
        TRBODY(2, sacc[2], y2n[2], true)
        TRBODY(3, sacc[3], y2n[3], true)
        __builtin_amdgcn_s_setprio(0);
        asm volatile("s_waitcnt vmcnt(0)" ::: "memory");
        __builtin_amdgcn_s_barrier();
        __builtin_amdgcn_sched_barrier(0);
        __builtin_amdgcn_s_setprio(1);
        PVMFMA
        __builtin_amdgcn_s_setprio(0);
    }

    float den[4];
#pragma unroll
    for (int r = 0; r < 4; ++r) {
        float s = wsum[r];
        s += __shfl_xor(s, 1);
        s += __shfl_xor(s, 2);
        s += __shfl_xor(s, 4);
        s += __shfl_xor(s, 8);
        den[r] = s;
    }
#pragma unroll
    for (int r = 0; r < 4; ++r) {
        const float iv = __builtin_amdgcn_rcpf(den[r]);
        const size_t rowb = (size_t)(b * TT + rg * 16 + lg * 4 + r) * CC + h * 64;
#pragma unroll
        for (int n = 0; n < 4; ++n) {
            const float val = pv[n][r] * iv;
            const ushort hb = f2bf(val);
            yh[rowb + n * 16 + lr] = hb;
            yl[rowb + n * 16 + lr] = f2bf(val - bf2f(hb));
        }
    }
#undef TRBODY
#undef SMFMA
#undef PVMFMA
#undef STAGE_K
#undef STAGE_V
}

// ---------------- output GEMM: dbuf gl_lds staging, counted vmcnt (R12) ----------------
__global__ __launch_bounds__(256) void gemm_out(const ushort* __restrict__ Ahp,
                                                const ushort* __restrict__ Alp,
                                                const ushort* __restrict__ Wh,
                                                const ushort* __restrict__ Wl,
                                                float* __restrict__ C) {
    __shared__ ushort Ah[2][32 * 64], Al[2][32 * 64], Bh[2][32 * 64], Bl[2][32 * 64];
    const int tid = threadIdx.x, lane = tid & 63, wv = tid >> 6;
    const int wr = wv >> 1, wc = wv & 1, lr = lane & 15, lg = lane >> 4;
    const int m0 = blockIdx.x * 64, n0 = blockIdx.y * 64;

    const int sp = 8 * wv + (lane >> 3);
    const int sg = (lane & 7) ^ (sp & 7);
    const int srow = 2 * sp + (sg >> 2);
    const int scol = (sg & 3) * 8;
    const size_t asrc = (size_t)(m0 + srow) * CC + scol;
    const size_t bsrc = (size_t)(n0 + srow) * CC + scol;
    const int goff = (((4 * (lr & 1) + lg) ^ ((lr >> 1) & 7)) << 4);
    const int pa = wr * 16 + (lr >> 1);
    const int pb = wc * 16 + (lr >> 1);

    f32x4 acc[2][2] = {};

#define STAGE_O(BUF, KK)                                                          \
    gl_lds16(Ahp + asrc + (KK), (char*)Ah[BUF] + wv * 1024);                      \
    gl_lds16(Alp + asrc + (KK), (char*)Al[BUF] + wv * 1024);                      \
    gl_lds16(Wh + bsrc + (KK), (char*)Bh[BUF] + wv * 1024);                       \
    gl_lds16(Wl + bsrc + (KK), (char*)Bl[BUF] + wv * 1024);

    STAGE_O(0, 0)
    int cur = 0;
    for (int kk = 0; kk < CC; kk += 32) {
        if (kk + 32 < CC) {
            STAGE_O(cur ^ 1, kk + 32)
            asm volatile("s_waitcnt vmcnt(4)" ::: "memory");
        } else {
            asm volatile("s_waitcnt vmcnt(0)" ::: "memory");
        }
        __builtin_amdgcn_s_barrier();
        __builtin_amdgcn_sched_barrier(0);
        bf16x8 a_h[2], a_l[2];
#pragma unroll
        for (int m = 0; m < 2; ++m) {
            const int off = (pa + m * 8) * 128 + goff;
            a_h[m] = *(const bf16x8*)((char*)Ah[cur] + off);
            a_l[m] = *(const bf16x8*)((char*)Al[cur] + off);
        }
#pragma unroll
        for (int n = 0; n < 2; ++n) {
            const int off = (pb + n * 8) * 128 + goff;
            bf16x8 b_h = *(const bf16x8*)((char*)Bh[cur] + off);
            bf16x8 b_l = *(const bf16x8*)((char*)Bl[cur] + off);
#pragma unroll
            for (int m = 0; m < 2; ++m) {
                acc[m][n] = MFMA(a_h[m], b_h, acc[m][n]);
                acc[m][n] = MFMA(a_h[m], b_l, acc[m][n]);
                acc[m][n] = MFMA(a_l[m], b_h, acc[m][n]);
            }
        }
        __builtin_amdgcn_s_barrier();
        cur ^= 1;
    }
#undef STAGE_O
#pragma unroll
    for (int m = 0; m < 2; ++m)
#pragma unroll
        for (int n = 0; n < 2; ++n)
#pragma unroll
            for (int r = 0; r < 4; ++r)
                C[(size_t)(m0 + wr * 32 + m * 16 + lg * 4 + r) * CC + n0 + wc * 32 + n * 16 + lr] =
                    acc[m][n][r];
}

extern "C" void kernel_launch(void* const* d_in, const int* in_sizes, int n_in,
                              void* d_out, int out_size, void* d_ws, size_t ws_size,
                              hipStream_t stream) {
    const float* x     = (const float*)d_in[0];
    const float* Wqkv  = (const float*)d_in[1];
    const float* Wproj = (const float*)d_in[2];
    const float* kcurv = (const float*)d_in[3];
    float* out = (float*)d_out;

    const size_t PL = (size_t)4096 * CC;
    char* w = (char*)d_ws;
    const bool ps = ws_size >= 53870592ULL;

    ushort *xh, *xl, *qh, *ql, *kh, *kl, *vT, *Wqh, *Wql, *Wph, *Wpl, *yh, *yl;
    float *x2g, *y2g;
    if (ps) {
        xh = (ushort*)w;          xl = xh + PL;
        qh = xl + PL;  ql = qh + PL;  kh = ql + PL;  kl = kh + PL;  vT = kl + PL;
        Wqh = vT + PL;            Wql = Wqh + (size_t)2304 * CC;
        Wph = Wql + (size_t)2304 * CC;  Wpl = Wph + (size_t)CC * CC;
        x2g = (float*)(Wpl + (size_t)CC * CC);  y2g = x2g + 48 * TT;
        yh = (ushort*)w;  yl = yh + PL;
    } else {
        Wqh = (ushort*)w;  Wql = Wqh + (size_t)2304 * CC;
        yh = (ushort*)w;   yl = yh + PL;
        qh = (ushort*)(w + 2 * PL * 2);
        ql = qh + PL;  kh = ql + PL;  kl = kh + PL;  vT = kl + PL;
        Wph = vT + PL;  Wpl = Wph + (size_t)CC * CC;
        x2g = (float*)(Wpl + (size_t)CC * CC);  y2g = x2g + 48 * TT;
        xh = xl = nullptr;
    }

    const int nprep = ps ? (2304 * CC + CC * CC + 4096 * CC) / 4 / 256
                         : (2304 * CC + CC * CC) / 4 / 256;
    wprep2<<<nprep, 256, 0, stream>>>(Wqkv, Wproj, x, Wqh, Wql, Wph, Wpl, xh, xl);
    if (ps)
        gemm_qkv<true><<<dim3(32, 18), 256, 0, stream>>>(x, xh, xl, Wqh, Wql, kcurv,
                                                         qh, ql, kh, kl, vT, x2g, y2g);
    else
        gemm_qkv<false><<<dim3(32, 18), 256, 0, stream>>>(x, nullptr, nullptr, Wqh, Wql,
                                                          kcurv, qh, ql, kh, kl, vT, x2g, y2g);
    hyp_attn<<<768, 256, 0, stream>>>(qh, ql, kh, kl, vT, x2g, y2g, kcurv, yh, yl);
    gemm_out<<<dim3(64, 12), 256, 0, stream>>>(yh, yl, Wph, Wpl, out);
}

// Round 20
// 130.694 us; speedup vs baseline: 1.1282x; 1.1282x over previous
//
#include <hip/hip_runtime.h>
#include <hip/hip_bf16.h>
#include <math.h>

#define PROJ_EPSF 0.004f
#define MIN_NORMF 1e-15f
#define ATANH_EPSF 1e-5f
#define WEI_EPSF 1e-3f
#define LN2F 0.69314718055994531f

#define TT 1024
#define CC 768
#define HH 12
#define BBATCH 4

typedef unsigned long long ull;
typedef __attribute__((ext_vector_type(4))) float f32x4;
typedef __attribute__((ext_vector_type(8))) short bf16x8;

#define MFMA(a, b, c) __builtin_amdgcn_mfma_f32_16x16x32_bf16(a, b, c, 0, 0, 0)

static __device__ __forceinline__ uint cvtpk(float a, float b) {
    uint r;
    asm("v_cvt_pk_bf16_f32 %0, %1, %2" : "=v"(r) : "v"(a), "v"(b));
    return r;
}
static __device__ __forceinline__ ushort f2bf(float f) {
    uint u = __float_as_uint(f);
    u += 0x7fffu + ((u >> 16) & 1u);
    return (ushort)(u >> 16);
}
static __device__ __forceinline__ float bf2f(ushort h) {
    return __uint_as_float(((uint)h) << 16);
}
static __device__ __forceinline__ void split4(const float4& f, ull& hp, ull& lp) {
    uint h01 = cvtpk(f.x, f.y), h23 = cvtpk(f.z, f.w);
    float r0 = f.x - __uint_as_float(h01 << 16);
    float r1 = f.y - __uint_as_float(h01 & 0xffff0000u);
    float r2 = f.z - __uint_as_float(h23 << 16);
    float r3 = f.w - __uint_as_float(h23 & 0xffff0000u);
    uint l01 = cvtpk(r0, r1), l23 = cvtpk(r2, r3);
    hp = ((ull)h23 << 32) | h01;
    lp = ((ull)l23 << 32) | l01;
}
union pk16 { bf16x8 v; ull u[2]; };
static __device__ __forceinline__ void gl_lds16(const void* g, void* l) {
    __builtin_amdgcn_global_load_lds(
        (const __attribute__((address_space(1))) unsigned int*)g,
        (__attribute__((address_space(3))) unsigned int*)l, 16, 0, 0);
}

// ---------------- prep: weights (+x when PS) -> bf16 hi/lo planes ----------------
__global__ __launch_bounds__(256) void wprep2(const float* __restrict__ Wq,
                                              const float* __restrict__ Wp,
                                              const float* __restrict__ x,
                                              ushort* __restrict__ Wqh,
                                              ushort* __restrict__ Wql,
                                              ushort* __restrict__ Wph,
                                              ushort* __restrict__ Wpl,
                                              ushort* __restrict__ xh,
                                              ushort* __restrict__ xl) {
    const int n1 = 2304 * CC / 4;
    const int n2 = CC * CC / 4;
    const int n3 = 4096 * CC / 4;
    int i = blockIdx.x * 256 + threadIdx.x;
    if (i < n1) {
        float4 f = ((const float4*)Wq)[i];
        ull hp, lp;
        split4(f, hp, lp);
        ((ull*)Wqh)[i] = hp;
        ((ull*)Wql)[i] = lp;
    } else if (i < n1 + n2) {
        int j = i - n1;
        float4 f = ((const float4*)Wp)[j];
        ull hp, lp;
        split4(f, hp, lp);
        ((ull*)Wph)[j] = hp;
        ((ull*)Wpl)[j] = lp;
    } else if (xh && i < n1 + n2 + n3) {
        int j = i - n1 - n2;
        float4 f = ((const float4*)x)[j];
        ull hp, lp;
        split4(f, hp, lp);
        ((ull*)xh)[j] = hp;
        ((ull*)xl)[j] = lp;
    }
}

// ---------------- fused QKV GEMM (R16 proven: dbuf gl_lds, 1 barrier/iter) ----------------
template <bool PS>
__global__ __launch_bounds__(256) void gemm_qkv(
        const float* __restrict__ x, const ushort* __restrict__ xhp,
        const ushort* __restrict__ xlp, const ushort* __restrict__ Wh,
        const ushort* __restrict__ Wl, const float* __restrict__ kcurv,
        ushort* __restrict__ qh, ushort* __restrict__ ql,
        ushort* __restrict__ kh, ushort* __restrict__ kl,
        ushort* __restrict__ vT, float* __restrict__ x2g,
        float* __restrict__ y2g) {
    __shared__ ushort SS[2][4][4096];
    const int tid = threadIdx.x, lane = tid & 63, wv = tid >> 6;
    const int wr = wv >> 1, wc = wv & 1, lr = lane & 15, lg = lane >> 4;
    const int m0 = blockIdx.x * 128, n0 = blockIdx.y * 128;
    const bool isV = (n0 >= 2 * CC);

    const int c0 = 2 * wv, c1 = 2 * wv + 1;
    const int p0 = 8 * c0 + (lane >> 3), q0 = (lane & 7) ^ (p0 & 7);
    const int p1 = 8 * c1 + (lane >> 3), q1 = (lane & 7) ^ (p1 & 7);
    const size_t bs0 = (size_t)(n0 + 2 * p0 + (q0 >> 2)) * CC + (q0 & 3) * 8;
    const size_t bs1 = (size_t)(n0 + 2 * p1 + (q1 >> 2)) * CC + (q1 & 3) * 8;
    const size_t as0 = (size_t)(m0 + 2 * p0 + (q0 >> 2)) * CC + (q0 & 3) * 8;
    const size_t as1 = (size_t)(m0 + 2 * p1 + (q1 >> 2)) * CC + (q1 & 3) * 8;
    const int arow = tid >> 1, akh = tid & 1;
    const float* Ap = x + (size_t)(m0 + arow) * CC + akh * 16;
    const int ap_ = arow >> 1;
    const int ag0 = 4 * (arow & 1) + 2 * akh;
    const int aoff0 = ap_ * 128 + ((ag0 ^ (ap_ & 7)) << 4);
    const int aoff1 = ap_ * 128 + (((ag0 + 1) ^ (ap_ & 7)) << 4);
    const int goff = (((4 * (lr & 1) + lg) ^ ((lr >> 1) & 7)) << 4);
    const int pa = wr * 32 + (lr >> 1);
    const int pb = wc * 32 + (lr >> 1);

    f32x4 acc[4][4] = {};
    float4 av[4];

#define STAGE_B(BUF, KK)                                                          \
    gl_lds16(Wh + bs0 + (KK), (char*)SS[BUF][2] + c0 * 1024);                     \
    gl_lds16(Wh + bs1 + (KK), (char*)SS[BUF][2] + c1 * 1024);                     \
    if (!isV) {                                                                   \
        gl_lds16(Wl + bs0 + (KK), (char*)SS[BUF][3] + c0 * 1024);                 \
        gl_lds16(Wl + bs1 + (KK), (char*)SS[BUF][3] + c1 * 1024);                 \
    }
#define STAGE_APS(BUF, KK)                                                        \
    gl_lds16(xhp + as0 + (KK), (char*)SS[BUF][0] + c0 * 1024);                    \
    gl_lds16(xhp + as1 + (KK), (char*)SS[BUF][0] + c1 * 1024);                    \
    if (!isV) {                                                                   \
        gl_lds16(xlp + as0 + (KK), (char*)SS[BUF][1] + c0 * 1024);                \
        gl_lds16(xlp + as1 + (KK), (char*)SS[BUF][1] + c1 * 1024);                \
    }
#define SPLIT_A(BUF)                                                              \
    {                                                                             \
        pk16 h_, l_;                                                              \
        split4(av[0], h_.u[0], l_.u[0]);                                          \
        split4(av[1], h_.u[1], l_.u[1]);                                          \
        *(bf16x8*)((char*)SS[BUF][0] + aoff0) = h_.v;                             \
        if (!isV) *(bf16x8*)((char*)SS[BUF][1] + aoff0) = l_.v;                   \
        split4(av[2], h_.u[0], l_.u[0]);                                          \
        split4(av[3], h_.u[1], l_.u[1]);                                          \
        *(bf16x8*)((char*)SS[BUF][0] + aoff1) = h_.v;                             \
        if (!isV) *(bf16x8*)((char*)SS[BUF][1] + aoff1) = l_.v;                   \
    }
#define LOAD_A(KK)                                                                \
    { _Pragma("unroll") for (int q = 0; q < 4; ++q)                               \
        av[q] = *(const float4*)(Ap + (KK) + 4 * q); }
#define DO_MFMA(BUF)                                                              \
    if (!isV) {                                                                   \
        bf16x8 a_h[4], a_l[4];                                                    \
        _Pragma("unroll") for (int m = 0; m < 4; ++m) {                           \
            const int off = (pa + m * 8) * 128 + goff;                            \
            a_h[m] = *(const bf16x8*)((char*)SS[BUF][0] + off);                   \
            a_l[m] = *(const bf16x8*)((char*)SS[BUF][1] + off);                   \
        }                                                                         \
        _Pragma("unroll") for (int n = 0; n < 4; ++n) {                           \
            const int off = (pb + n * 8) * 128 + goff;                            \
            bf16x8 b_h = *(const bf16x8*)((char*)SS[BUF][2] + off);               \
            bf16x8 b_l = *(const bf16x8*)((char*)SS[BUF][3] + off);               \
            _Pragma("unroll") for (int m = 0; m < 4; ++m) {                       \
                acc[m][n] = MFMA(a_h[m], b_h, acc[m][n]);                         \
                acc[m][n] = MFMA(a_h[m], b_l, acc[m][n]);                         \
                acc[m][n] = MFMA(a_l[m], b_h, acc[m][n]);                         \
            }                                                                     \
        }                                                                         \
    } else {                                                                      \
        bf16x8 a_h[4], b_h[4];                                                    \
        _Pragma("unroll") for (int m = 0; m < 4; ++m)                             \
            a_h[m] = *(const bf16x8*)((char*)SS[BUF][0] + (pa + m * 8) * 128 + goff); \
        _Pragma("unroll") for (int n = 0; n < 4; ++n)                             \
            b_h[n] = *(const bf16x8*)((char*)SS[BUF][2] + (pb + n * 8) * 128 + goff); \
        _Pragma("unroll") for (int n = 0; n < 4; ++n)                             \
            _Pragma("unroll") for (int m = 0; m < 4; ++m)                         \
                acc[n][m] = MFMA(b_h[n], a_h[m], acc[n][m]);                      \
    }

    int cur = 0;
    if constexpr (PS) {
        STAGE_APS(0, 0)
        STAGE_B(0, 0)
        asm volatile("s_waitcnt vmcnt(0)" ::: "memory");
        __builtin_amdgcn_s_barrier();
        __builtin_amdgcn_sched_barrier(0);
        for (int kk = 0; kk < CC; kk += 32) {
            const bool notLast = (kk + 32 < CC);
            if (notLast) {
                STAGE_APS(cur ^ 1, kk + 32)
                STAGE_B(cur ^ 1, kk + 32)
                __builtin_amdgcn_sched_barrier(0);
            }
            DO_MFMA(cur)
            if (notLast) {
                asm volatile("s_waitcnt vmcnt(0)" ::: "memory");
                __builtin_amdgcn_s_barrier();
                __builtin_amdgcn_sched_barrier(0);
            }
            cur ^= 1;
        }
    } else {
        LOAD_A(0)
        STAGE_B(0, 0)
        SPLIT_A(0)
        LOAD_A(32)
        asm volatile("s_waitcnt vmcnt(4) lgkmcnt(0)" ::: "memory");
        __builtin_amdgcn_s_barrier();
        __builtin_amdgcn_sched_barrier(0);
        for (int kk = 0; kk < CC; kk += 32) {
            const bool notLast = (kk + 32 < CC);
            if (notLast) {
                STAGE_B(cur ^ 1, kk + 32)
                SPLIT_A(cur ^ 1)
                if (kk + 64 < CC) LOAD_A(kk + 64)
                __builtin_amdgcn_sched_barrier(0);
            }
            DO_MFMA(cur)
            if (notLast) {
                if (kk + 64 < CC)
                    asm volatile("s_waitcnt vmcnt(4) lgkmcnt(0)" ::: "memory");
                else
                    asm volatile("s_waitcnt vmcnt(0) lgkmcnt(0)" ::: "memory");
                __builtin_amdgcn_s_barrier();
                __builtin_amdgcn_sched_barrier(0);
            }
            cur ^= 1;
        }
    }
#undef STAGE_B
#undef STAGE_APS
#undef SPLIT_A
#undef LOAD_A
#undef DO_MFMA

    // ---- epilogue: per-wave LDS re-layout -> coalesced b128 stores ----
    __syncthreads();
    ushort* Shi = (ushort*)SS + (size_t)wv * 8192;
    ushort* Slo = Shi + 4096;
    const int rl = lane >> 3, cg = lane & 7;
    if (isV) {
        const int hd = (n0 - 2 * CC) / 64 + wc;
#pragma unroll
        for (int n = 0; n < 4; ++n)
#pragma unroll
            for (int m = 0; m < 4; ++m)
#pragma unroll
                for (int r = 0; r < 4; ++r)
                    Shi[(n * 16 + lg * 4 + r) * 64 + m * 16 + lr] = f2bf(acc[n][m][r]);
#pragma unroll
        for (int q = 0; q < 8; ++q) {
            const int dlr = q * 8 + rl;
            *(bf16x8*)&vT[(size_t)(hd * 64 + dlr) * 4096 + m0 + wr * 64 + cg * 8] =
                *(const bf16x8*)&Shi[dlr * 64 + cg * 8];
        }
    } else {
        const bool isQ = (n0 < CC);
        const int hd = (isQ ? n0 : n0 - CC) / 64 + wc;
        ushort* ph = isQ ? qh : kh;
        ushort* pl = isQ ? ql : kl;
        float* sg = isQ ? x2g : y2g;
        const float kcv = kcurv[hd];
        const float mxn = (1.0f - PROJ_EPSF) / sqrtf(kcv);
        const float mxn2 = mxn * mxn;
#pragma unroll
        for (int m = 0; m < 4; ++m)
#pragma unroll
            for (int r = 0; r < 4; ++r) {
                float s = 0.f;
#pragma unroll
                for (int n = 0; n < 4; ++n) s = fmaf(acc[m][n][r], acc[m][n][r], s);
                s += __shfl_xor(s, 1);
                s += __shfl_xor(s, 2);
                s += __shfl_xor(s, 4);
                s += __shfl_xor(s, 8);
                float scale = 1.0f, x2v = s;
                if (s > mxn2) {
                    scale = mxn * __builtin_amdgcn_rcpf(sqrtf(s));
                    x2v = s * scale * scale;
                }
                const int row = m * 16 + lg * 4 + r;
#pragma unroll
                for (int n = 0; n < 4; ++n) {
                    const float v = acc[m][n][r] * scale;
                    const ushort hb = f2bf(v);
                    Shi[row * 64 + n * 16 + lr] = hb;
                    Slo[row * 64 + n * 16 + lr] = f2bf(v - bf2f(hb));
                }
                if (lr == 0) {
                    const int tok = m0 + wr * 64 + row;
                    sg[(size_t)((tok >> 10) * HH + hd) * TT + (tok & 1023)] = x2v;
                }
            }
        const size_t cb = (size_t)(isQ ? n0 : n0 - CC) + wc * 64;
#pragma unroll
        for (int q = 0; q < 8; ++q) {
            const int row = q * 8 + rl;
            const size_t gb = (size_t)(m0 + wr * 64 + row) * CC + cb + cg * 8;
            *(bf16x8*)&ph[gb] = *(const bf16x8*)&Shi[row * 64 + cg * 8];
            *(bf16x8*)&pl[gb] = *(const bf16x8*)&Slo[row * 64 + cg * 8];
        }
    }
}

// ---------------- 4-wave LDS-staged attention, counted vmcnt (R16 proven) ----------------
__global__ __launch_bounds__(256) void hyp_attn(
        const ushort* __restrict__ qh, const ushort* __restrict__ ql,
        const ushort* __restrict__ kh, const ushort* __restrict__ kl,
        const ushort* __restrict__ vT, const float* __restrict__ x2g,
        const float* __restrict__ y2g, const float* __restrict__ kcurv,
        ushort* __restrict__ yh, ushort* __restrict__ yl) {
    const int ib = (int)blockIdx.x;          // 0..767
    const int xcd = ib & 7, t = ib >> 3;
    const int tcr = t / 6;
    const int which = t - tcr * 6;
    const int g64 = 15 - tcr;
    const int bh = which * 8 + xcd;
    const int b = bh / HH, h = bh - b * HH;
    const int tid = threadIdx.x, lane = tid & 63, wv = tid >> 6;
    const int lr = lane & 15, lg = lane >> 4;
    const int rg = g64 * 4 + wv;
    const int rgq = g64;

    __shared__ char ldsK[2][16384];
    __shared__ char ldsV[8192];
    __shared__ ushort wtb[4][16 * 72];
    ushort* wtw = wtb[wv];

    const float kc = kcurv[h];
    const float sk = sqrtf(kc);
    const float distc = LN2F / sk;
    const float d2c = distc * distc;
    const float twokc = 2.0f * kc;
    const float cA = 1.0f - ATANH_EPSF;

    const size_t qrb = (size_t)(b * TT + rg * 16 + lr) * CC + h * 64 + lg * 8;
    const bf16x8 qH0 = *(const bf16x8*)(qh + qrb), qH1 = *(const bf16x8*)(qh + qrb + 32);
    const bf16x8 qL0 = *(const bf16x8*)(ql + qrb), qL1 = *(const bf16x8*)(ql + qrb + 32);
    const float4 x2v = *(const float4*)&x2g[(size_t)bh * TT + rg * 16 + lg * 4];
    const float x2a[4] = { x2v.x, x2v.y, x2v.z, x2v.w };
    float kx2[4], Bc[4], Bc2[4];
#pragma unroll
    for (int r = 0; r < 4; ++r) {
        kx2[r] = kc * x2a[r];
        Bc[r] = 1.0f - kx2[r];
        Bc2[r] = Bc[r] * Bc[r];
    }

    const int srow8 = lane >> 3;
    const int sgrp = (lane & 7) ^ (srow8 & 7);
    const int so0 = ((lg ^ (lr & 7)) << 4);
    const int so1 = (((4 + lg) ^ (lr & 7)) << 4);
    const int lro = lr << 7;

#define STAGE_K(BUF, J0)                                                          \
    { _Pragma("unroll") for (int c4 = 0; c4 < 2; ++c4) {                          \
        const int c = wv * 2 + c4;                                                \
        const size_t gsrc = (size_t)(b * TT + (J0) + c * 8 + srow8) * CC + h * 64 + sgrp * 8; \
        gl_lds16(kh + gsrc, (char*)(BUF) + c * 1024);                             \
        gl_lds16(kl + gsrc, (char*)(BUF) + 8192 + c * 1024);                      \
    } }
#define STAGE_V(J0)                                                               \
    { _Pragma("unroll") for (int c4 = 0; c4 < 2; ++c4) {                          \
        const int c = wv * 2 + c4;                                                \
        gl_lds16(vT + (size_t)(h * 64 + c * 8 + srow8) * 4096 + b * TT + (J0) + sgrp * 8, \
                 ldsV + c * 1024);                                                \
    } }

#define TRANSF(NN, SA, Y2R)                                                        \
    {                                                                              \
        const float ky2 = kc * (Y2R);                                              \
        const float p1 = 1.0f + ky2;                                               \
        const int jg = j0 + NN * 16 + lr;                                          \
        _Pragma("unroll") for (int r = 0; r < 4; ++r) {                            \
            const float xy = SA[r];                                                \
            const float t2 = twokc * xy;                                           \
            const float Aa = p1 - t2;                                              \
            const float dn = fmaxf(fmaf(kx2[r], ky2, 1.0f) - t2, MIN_NORMF);       \
            const float ABxy = Aa * (Bc[r] * xy);                                  \
            const float c1 = fmaf(Bc2[r], (Y2R), -2.0f * ABxy);                    \
            const float num2 = fmaf(Aa * Aa, x2a[r], c1);                          \
            const float s = sqrtf(fmaxf(num2, MIN_NORMF));                         \
            const float sm = fminf(sk * s, cA * dn);                               \
            const float L = __builtin_amdgcn_logf((dn + sm) *                      \
                                __builtin_amdgcn_rcpf(dn - sm));                   \
            float w = __builtin_amdgcn_rcpf(fmaf(L * L, d2c, WEI_EPSF));           \
            if (mk && (jg > rg * 16 + lg * 4 + r)) w = 0.0f;                       \
            wtw[(lg * 4 + r) * 72 + NN * 16 + lr] = f2bf(w);                       \
            wsum[r] += w;                                                          \
        }                                                                          \
    }

    f32x4 pv[4] = {};
    float wsum[4] = {};

    STAGE_K(ldsK[0], 0)

    int cur = 0;
    for (int jt = 0; jt <= rgq; ++jt) {
        const int j0 = jt * 64;
        const bool mk = (jt == rgq);
        STAGE_V(j0)
        if (jt < rgq) {
            STAGE_K(ldsK[cur ^ 1], j0 + 64)
            asm volatile("s_waitcnt vmcnt(6)" ::: "memory");
        } else {
            asm volatile("s_waitcnt vmcnt(2)" ::: "memory");
        }
        __builtin_amdgcn_s_barrier();
        __builtin_amdgcn_sched_barrier(0);
        const size_t y2b = (size_t)bh * TT + j0 + lr;
        const float y2n[4] = { y2g[y2b], y2g[y2b + 16], y2g[y2b + 32], y2g[y2b + 48] };
        __builtin_amdgcn_s_setprio(1);
        f32x4 sacc[4] = {};
#pragma unroll
        for (int n = 0; n < 4; ++n) {
            const char* p = ldsK[cur] + n * 2048 + lro;
            bf16x8 h0 = *(const bf16x8*)(p + so0);
            bf16x8 h1 = *(const bf16x8*)(p + so1);
            bf16x8 l0 = *(const bf16x8*)(p + 8192 + so0);
            bf16x8 l1 = *(const bf16x8*)(p + 8192 + so1);
            sacc[n] = MFMA(qH0, h0, sacc[n]);
            sacc[n] = MFMA(qH0, l0, sacc[n]);
            sacc[n] = MFMA(qL0, h0, sacc[n]);
            sacc[n] = MFMA(qH1, h1, sacc[n]);
            sacc[n] = MFMA(qH1, l1, sacc[n]);
            sacc[n] = MFMA(qL1, h1, sacc[n]);
        }
        TRANSF(0, sacc[0], y2n[0])
        TRANSF(1, sacc[1], y2n[1])
        TRANSF(2, sacc[2], y2n[2])
        TRANSF(3, sacc[3], y2n[3])
        __builtin_amdgcn_s_setprio(0);
        if (jt < rgq)
            asm volatile("s_waitcnt vmcnt(4)" ::: "memory");
        else
            asm volatile("s_waitcnt vmcnt(0)" ::: "memory");
        __builtin_amdgcn_s_barrier();
        __builtin_amdgcn_sched_barrier(0);
        __builtin_amdgcn_s_setprio(1);
        bf16x8 pw0 = *(const bf16x8*)&wtw[lr * 72 + lg * 8];
        bf16x8 pw1 = *(const bf16x8*)&wtw[lr * 72 + 32 + lg * 8];
#pragma unroll
        for (int n = 0; n < 4; ++n) {
            const char* p = ldsV + n * 2048 + lro;
            bf16x8 v0 = *(const bf16x8*)(p + so0);
            bf16x8 v1 = *(const bf16x8*)(p + so1);
            pv[n] = MFMA(pw0, v0, pv[n]);
            pv[n] = MFMA(pw1, v1, pv[n]);
        }
        __builtin_amdgcn_s_setprio(0);
        __builtin_amdgcn_s_barrier();
        cur ^= 1;
    }

    float den[4];
#pragma unroll
    for (int r = 0; r < 4; ++r) {
        float s = wsum[r];
        s += __shfl_xor(s, 1);
        s += __shfl_xor(s, 2);
        s += __shfl_xor(s, 4);
        s += __shfl_xor(s, 8);
        den[r] = s;
    }
#pragma unroll
    for (int r = 0; r < 4; ++r) {
        const float iv = __builtin_amdgcn_rcpf(den[r]);
        const size_t rowb = (size_t)(b * TT + rg * 16 + lg * 4 + r) * CC + h * 64;
#pragma unroll
        for (int n = 0; n < 4; ++n) {
            const float val = pv[n][r] * iv;
            const ushort hb = f2bf(val);
            yh[rowb + n * 16 + lr] = hb;
            yl[rowb + n * 16 + lr] = f2bf(val - bf2f(hb));
        }
    }
#undef TRANSF
#undef STAGE_K
#undef STAGE_V
}

// ---------------- output GEMM: dbuf gl_lds staging, counted vmcnt (R12) ----------------
__global__ __launch_bounds__(256) void gemm_out(const ushort* __restrict__ Ahp,
                                                const ushort* __restrict__ Alp,
                                                const ushort* __restrict__ Wh,
                                                const ushort* __restrict__ Wl,
                                                float* __restrict__ C) {
    __shared__ ushort Ah[2][32 * 64], Al[2][32 * 64], Bh[2][32 * 64], Bl[2][32 * 64];
    const int tid = threadIdx.x, lane = tid & 63, wv = tid >> 6;
    const int wr = wv >> 1, wc = wv & 1, lr = lane & 15, lg = lane >> 4;
    const int m0 = blockIdx.x * 64, n0 = blockIdx.y * 64;

    const int sp = 8 * wv + (lane >> 3);
    const int sg = (lane & 7) ^ (sp & 7);
    const int srow = 2 * sp + (sg >> 2);
    const int scol = (sg & 3) * 8;
    const size_t asrc = (size_t)(m0 + srow) * CC + scol;
    const size_t bsrc = (size_t)(n0 + srow) * CC + scol;
    const int goff = (((4 * (lr & 1) + lg) ^ ((lr >> 1) & 7)) << 4);
    const int pa = wr * 16 + (lr >> 1);
    const int pb = wc * 16 + (lr >> 1);

    f32x4 acc[2][2] = {};

#define STAGE_O(BUF, KK)                                                          \
    gl_lds16(Ahp + asrc + (KK), (char*)Ah[BUF] + wv * 1024);                      \
    gl_lds16(Alp + asrc + (KK), (char*)Al[BUF] + wv * 1024);                      \
    gl_lds16(Wh + bsrc + (KK), (char*)Bh[BUF] + wv * 1024);                       \
    gl_lds16(Wl + bsrc + (KK), (char*)Bl[BUF] + wv * 1024);

    STAGE_O(0, 0)
    int cur = 0;
    for (int kk = 0; kk < CC; kk += 32) {
        if (kk + 32 < CC) {
            STAGE_O(cur ^ 1, kk + 32)
            asm volatile("s_waitcnt vmcnt(4)" ::: "memory");
        } else {
            asm volatile("s_waitcnt vmcnt(0)" ::: "memory");
        }
        __builtin_amdgcn_s_barrier();
        __builtin_amdgcn_sched_barrier(0);
        bf16x8 a_h[2], a_l[2];
#pragma unroll
        for (int m = 0; m < 2; ++m) {
            const int off = (pa + m * 8) * 128 + goff;
            a_h[m] = *(const bf16x8*)((char*)Ah[cur] + off);
            a_l[m] = *(const bf16x8*)((char*)Al[cur] + off);
        }
#pragma unroll
        for (int n = 0; n < 2; ++n) {
            const int off = (pb + n * 8) * 128 + goff;
            bf16x8 b_h = *(const bf16x8*)((char*)Bh[cur] + off);
            bf16x8 b_l = *(const bf16x8*)((char*)Bl[cur] + off);
#pragma unroll
            for (int m = 0; m < 2; ++m) {
                acc[m][n] = MFMA(a_h[m], b_h, acc[m][n]);
                acc[m][n] = MFMA(a_h[m], b_l, acc[m][n]);
                acc[m][n] = MFMA(a_l[m], b_h, acc[m][n]);
            }
        }
        __builtin_amdgcn_s_barrier();
        cur ^= 1;
    }
#undef STAGE_O
#pragma unroll
    for (int m = 0; m < 2; ++m)
#pragma unroll
        for (int n = 0; n < 2; ++n)
#pragma unroll
            for (int r = 0; r < 4; ++r)
                C[(size_t)(m0 + wr * 32 + m * 16 + lg * 4 + r) * CC + n0 + wc * 32 + n * 16 + lr] =
                    acc[m][n][r];
}

extern "C" void kernel_launch(void* const* d_in, const int* in_sizes, int n_in,
                              void* d_out, int out_size, void* d_ws, size_t ws_size,
                              hipStream_t stream) {
    const float* x     = (const float*)d_in[0];
    const float* Wqkv  = (const float*)d_in[1];
    const float* Wproj = (const float*)d_in[2];
    const float* kcurv = (const float*)d_in[3];
    float* out = (float*)d_out;

    const size_t PL = (size_t)4096 * CC;
    char* w = (char*)d_ws;
    const bool ps = ws_size >= 53870592ULL;

    ushort *xh, *xl, *qh, *ql, *kh, *kl, *vT, *Wqh, *Wql, *Wph, *Wpl, *yh, *yl;
    float *x2g, *y2g;
    if (ps) {
        xh = (ushort*)w;          xl = xh + PL;
        qh = xl + PL;  ql = qh + PL;  kh = ql + PL;  kl = kh + PL;  vT = kl + PL;
        Wqh = vT + PL;            Wql = Wqh + (size_t)2304 * CC;
        Wph = Wql + (size_t)2304 * CC;  Wpl = Wph + (size_t)CC * CC;
        x2g = (float*)(Wpl + (size_t)CC * CC);  y2g = x2g + 48 * TT;
        yh = (ushort*)w;  yl = yh + PL;
    } else {
        Wqh = (ushort*)w;  Wql = Wqh + (size_t)2304 * CC;
        yh = (ushort*)w;   yl = yh + PL;
        qh = (ushort*)(w + 2 * PL * 2);
        ql = qh + PL;  kh = ql + PL;  kl = kh + PL;  vT = kl + PL;
        Wph = vT + PL;  Wpl = Wph + (size_t)CC * CC;
        x2g = (float*)(Wpl + (size_t)CC * CC);  y2g = x2g + 48 * TT;
        xh = xl = nullptr;
    }

    const int nprep = ps ? (2304 * CC + CC * CC + 4096 * CC) / 4 / 256
                         : (2304 * CC + CC * CC) / 4 / 256;
    wprep2<<<nprep, 256, 0, stream>>>(Wqkv, Wproj, x, Wqh, Wql, Wph, Wpl, xh, xl);
    if (ps)
        gemm_qkv<true><<<dim3(32, 18), 256, 0, stream>>>(x, xh, xl, Wqh, Wql, kcurv,
                                                         qh, ql, kh, kl, vT, x2g, y2g);
    else
        gemm_qkv<false><<<dim3(32, 18), 256, 0, stream>>>(x, nullptr, nullptr, Wqh, Wql,
                                                          kcurv, qh, ql, kh, kl, vT, x2g, y2g);
    hyp_attn<<<768, 256, 0, stream>>>(qh, ql, kh, kl, vT, x2g, y2g, kcurv, yh, yl);
    gemm_out<<<dim3(64, 12), 256, 0, stream>>>(yh, yl, Wph, Wpl, out);
}